// Round 5
// baseline (131.410 us; speedup 1.0000x reference)
//
#include <hip/hip_runtime.h>
#include <math.h>

#define KN 16
#define DM 256
#define NS 3
#define NE 120
#define NT_TRI 560
#define NBATCH 512
#define TAUF 1e-4f
#define KAUG 1600            // 1536 + 6 bias cols + 58 zero pad

typedef unsigned short ushort_t;
typedef __attribute__((ext_vector_type(8))) short short8v;
typedef __attribute__((ext_vector_type(4))) short short4v;
typedef __attribute__((ext_vector_type(4))) float f32x4;

// ---- workspace byte offsets (~30.8 MB total) ----
#define OFF_WSTACK 0u          // bf16 [256][1600]                       819200
#define OFF_WF1T   819200u     // bf16 [1024][256]                       524288
#define OFF_WF2T   1343488u    // bf16 [256][1024]                       524288
#define OFF_Z      1867776u    // bf16 [8192][1600]                    26214400
#define OFF_H      1867776u    // bf16 [8192][1024] aliases Z (Z dead by then)
#define OFF_LN2    28082176u   // bf16 [8192][256]                      4194304

__device__ __forceinline__ ushort_t f2bf(float f) {
    union { float f; unsigned int u; } v; v.f = f;
    unsigned int r = v.u + 0x7FFFu + ((v.u >> 16) & 1u);
    return (ushort_t)(r >> 16);
}
__device__ __forceinline__ void gload_lds16(const void* g, void* l) {
    auto gp = (const __attribute__((address_space(1))) unsigned int*)(unsigned long long)(g);
    auto lp = (__attribute__((address_space(3))) unsigned int*)(unsigned long long)(l);
    __builtin_amdgcn_global_load_lds(gp, lp, 16, 0, 0);
}

// ---------------------------------------------------------------------------
// Prep kernel: bid<102 -> fuse Wv0/We x Wout into Wstack[1600 cols] + bias rows
//              bid<166 -> transpose Wf1 -> wf1t ; else Wf2 -> wf2t
// ---------------------------------------------------------------------------
__global__ __launch_bounds__(256) void prep_kernel(
    const float* __restrict__ Wv0, const float* __restrict__ bv0,
    const float* __restrict__ We,  const float* __restrict__ be,
    const float* __restrict__ Wout,
    const float* __restrict__ Wf1, const float* __restrict__ Wf2,
    ushort_t* __restrict__ wstack, ushort_t* __restrict__ wf1t,
    ushort_t* __restrict__ wf2t)
{
    __shared__ float lhs[16][DM];       // fuse branch
    __shared__ float tile[64][65];      // transpose branch
    const int bid = blockIdx.x;
    const int j = threadIdx.x;

    if (bid < 102) {
        const int m = bid / 17, by = bid % 17;
        const int path = m / 3, s = m % 3;
        const float* __restrict__ Wo = Wout + (size_t)m*DM*DM;
        if (by == 16) {   // fused bias -> K-row 1536+m of Wstack
            const float* bv = (path == 0) ? bv0 : be;
            const float f = (path == 0) ? 1.0f : 0.5f;   // 1_E = 0.5*|B1|^T 1_K
            float acc = 0.f;
            for (int k = 0; k < DM; ++k)
                acc += bv[s*DM + k] * f * Wo[k*DM + j];
            wstack[(size_t)j*KAUG + 1536 + m] = f2bf(acc);
            if (m == 0)
                for (int c = 1542; c < KAUG; ++c)
                    wstack[(size_t)j*KAUG + c] = 0;
            return;
        }
        const float* src = (path == 0) ? Wv0 : We;
        const int i0 = by * 16;
        for (int r = 0; r < 16; ++r)
            lhs[r][j] = src[(size_t)(i0 + r)*(NS*DM) + s*DM + j];
        __syncthreads();
        float acc[16];
#pragma unroll
        for (int r = 0; r < 16; ++r) acc[r] = 0.f;
        for (int k = 0; k < DM; ++k) {
            const float w = Wo[k*DM + j];
#pragma unroll
            for (int r = 0; r < 16; ++r) acc[r] += lhs[r][k] * w;
        }
#pragma unroll
        for (int r = 0; r < 16; ++r)
            wstack[(size_t)j*KAUG + m*DM + i0 + r] = f2bf(acc[r]);
        return;
    }

    // transpose branches: fp32 [R][C] -> bf16 [C][R]
    const float* in; ushort_t* outp; int R, C, rt, ct;
    if (bid < 166) {
        const int q = bid - 102;                 // Wf1: 256x1024 -> 1024x256
        in = Wf1; outp = wf1t; R = 256; C = 1024;
        rt = (q >> 4) * 64; ct = (q & 15) * 64;
    } else {
        const int q = bid - 166;                 // Wf2: 1024x256 -> 256x1024
        in = Wf2; outp = wf2t; R = 1024; C = 256;
        rt = (q >> 2) * 64; ct = (q & 3) * 64;
    }
#pragma unroll
    for (int q2 = 0; q2 < 16; ++q2) {
        const int idx = q2*256 + j;
        const int r = idx >> 6, c = idx & 63;
        tile[r][c] = in[(size_t)(rt + r)*C + ct + c];
    }
    __syncthreads();
#pragma unroll
    for (int q2 = 0; q2 < 16; ++q2) {
        const int idx = q2*256 + j;
        const int cc = idx >> 6, rr = idx & 63;
        outp[(size_t)(ct + cc)*R + rt + rr] = f2bf(tile[rr][cc]);
    }
}

// ---------------------------------------------------------------------------
// Per-batch topology: LN -> P(reg butterfly) -> A_s -> T -> Z_aug via MFMA
// ---------------------------------------------------------------------------
__global__ __launch_bounds__(256) void attn_topo_kernel(
    const float* __restrict__ x, const float* __restrict__ mask,
    const int* __restrict__ e_i, const int* __restrict__ e_j,
    const int* __restrict__ t_ij, const int* __restrict__ t_jk, const int* __restrict__ t_ik,
    const float* __restrict__ log_scales,
    const float* __restrict__ Wg, const float* __restrict__ bg,
    const float* __restrict__ g1, const float* __restrict__ b1,
    ushort_t* __restrict__ Z)
{
    const int b = blockIdx.x;
    const int t = threadIdx.x;

    __shared__ ushort_t xnb[KN][DM];     // xn bf16, row-major (8 KB)
    __shared__ float Plds[KN][KN];
    __shared__ float pn[KN];
    __shared__ float msk[KN];
    __shared__ float sA[NS][KN][KN];
    __shared__ int   eidx[KN][KN];
    __shared__ float Qm[KN][KN];
    __shared__ float P2m[KN][KN];
    __shared__ float HQ[KN][KN];
    __shared__ float Hup[NS][KN][KN];
    __shared__ float Tm[2*NS][KN][20];   // padded rows (80 B, 16B-aligned)

    const int r  = t >> 4;
    const int cg = (t & 15) * 16;

    float xv[16];
    { // LayerNorm; keep normalized row-chunk in registers, bf16 copy to LDS
        const float* xr = x + (size_t)(b*KN + r)*DM + cg;
        float ssum = 0.f;
#pragma unroll
        for (int q = 0; q < 16; ++q) { xv[q] = xr[q]; ssum += xv[q]; }
#pragma unroll
        for (int o = 1; o < 16; o <<= 1) ssum += __shfl_xor(ssum, o);
        const float mu = ssum * (1.f/DM);
        float vsum = 0.f;
#pragma unroll
        for (int q = 0; q < 16; ++q) { float d = xv[q]-mu; vsum += d*d; }
#pragma unroll
        for (int o = 1; o < 16; o <<= 1) vsum += __shfl_xor(vsum, o);
        const float rstd = rsqrtf(vsum*(1.f/DM) + 1e-5f);
        short8v o0, o1;
#pragma unroll
        for (int q = 0; q < 16; ++q) {
            const int c = cg + q;
            xv[q] = (xv[q]-mu)*rstd*g1[c] + b1[c];
            if (q < 8) o0[q] = (short)f2bf(xv[q]); else o1[q-8] = (short)f2bf(xv[q]);
        }
        *(short8v*)&xnb[r][cg]     = o0;
        *(short8v*)&xnb[r][cg+8]   = o1;
        if (t < KN) msk[t] = mask[b*KN + t];
    }

    { // P[r][c] = sum_k xn[r][k]*Wg[k][c] + bg : per-thread partials over 16 k,
      // then 4-round shfl_xor butterfly across the 16 lanes sharing row r.
        float part[16];
#pragma unroll
        for (int c = 0; c < 16; ++c) part[c] = 0.f;
#pragma unroll
        for (int q = 0; q < 16; ++q) {
            const float xq = xv[q];
            const float* wr = Wg + (size_t)(cg + q)*KN;
            const f32x4 w0 = *(const f32x4*)(wr);
            const f32x4 w1 = *(const f32x4*)(wr + 4);
            const f32x4 w2 = *(const f32x4*)(wr + 8);
            const f32x4 w3 = *(const f32x4*)(wr + 12);
            part[0]  += xq*w0[0]; part[1]  += xq*w0[1]; part[2]  += xq*w0[2]; part[3]  += xq*w0[3];
            part[4]  += xq*w1[0]; part[5]  += xq*w1[1]; part[6]  += xq*w1[2]; part[7]  += xq*w1[3];
            part[8]  += xq*w2[0]; part[9]  += xq*w2[1]; part[10] += xq*w2[2]; part[11] += xq*w2[3];
            part[12] += xq*w3[0]; part[13] += xq*w3[1]; part[14] += xq*w3[2]; part[15] += xq*w3[3];
        }
        const int b0 = t & 1, b1b = (t>>1)&1, b2 = (t>>2)&1, b3 = (t>>3)&1;
        float p8[8];
#pragma unroll
        for (int c2 = 0; c2 < 8; ++c2) {
            const float keep = b0 ? part[2*c2+1] : part[2*c2];
            const float send = b0 ? part[2*c2]   : part[2*c2+1];
            p8[c2] = keep + __shfl_xor(send, 1);
        }
        float p4[4];
#pragma unroll
        for (int c2 = 0; c2 < 4; ++c2) {
            const float keep = b1b ? p8[2*c2+1] : p8[2*c2];
            const float send = b1b ? p8[2*c2]   : p8[2*c2+1];
            p4[c2] = keep + __shfl_xor(send, 2);
        }
        float p2v[2];
#pragma unroll
        for (int c2 = 0; c2 < 2; ++c2) {
            const float keep = b2 ? p4[2*c2+1] : p4[2*c2];
            const float send = b2 ? p4[2*c2]   : p4[2*c2+1];
            p2v[c2] = keep + __shfl_xor(send, 4);
        }
        {
            const float keep = b3 ? p2v[1] : p2v[0];
            const float send = b3 ? p2v[0] : p2v[1];
            Plds[r][t & 15] = keep + __shfl_xor(send, 8) + bg[t & 15];
        }
    }
    __syncthreads();
    if (t < KN) {
        float s = 0.f;
#pragma unroll
        for (int k = 0; k < KN; ++k) { const float p = Plds[t][k]; s += p*p; }
        pn[t] = s;
    }
    __syncthreads();

    { // distances -> A_s
        const int rr = t & 15, c = t >> 4;
        float dot = 0.f;
#pragma unroll
        for (int k = 0; k < KN; ++k) dot += Plds[rr][k]*Plds[c][k];
        float d2 = pn[rr] + pn[c] - 2.f*dot;
        const float m2 = msk[rr]*msk[c];
        const float dm = (d2 > 0.f) ? sqrtf(d2)*m2 : 0.f;
        const float dmsq = dm*dm;
#pragma unroll
        for (int s = 0; s < NS; ++s) {
            const float sig2 = expf(2.f*log_scales[s]);
            sA[s][rr][c] = expf(-dmsq/(2.f*sig2 + 1e-8f)) * m2;
        }
        eidx[rr][c] = -1;
    }
    __syncthreads();
    if (t < NE) {
        const int i = e_i[t], jn = e_j[t];
        eidx[i][jn] = t; eidx[jn][i] = t;
    }
    __syncthreads();

    { // Q, P2, L0_s, zero Hup
        const int n = t & 15, mcol = t >> 4;
        float q, p2;
        if (n != mcol) {
            const int e = eidx[n][mcol];
            if (e >= 0) { q = (mcol == e_j[e]) ? 1.f : -1.f; p2 = 1.f; }
            else        { q = 0.f; p2 = 0.f; }
        } else {
            q = 0.f; p2 = 0.f;
            for (int kk = 0; kk < KN; ++kk) {
                if (kk == n) continue;
                const int e = eidx[n][kk];
                if (e >= 0) { q += (n == e_j[e]) ? 1.f : -1.f; p2 += 1.f; }
            }
        }
        Qm[n][mcol] = q; P2m[n][mcol] = p2;
#pragma unroll
        for (int s = 0; s < NS; ++s) {
            float v;
            if (n != mcol) v = (eidx[n][mcol] >= 0) ? -sA[s][n][mcol] : 0.f;
            else {
                v = TAUF;
                for (int kk = 0; kk < KN; ++kk)
                    if (kk != n && eidx[n][kk] >= 0) v += sA[s][n][kk];
            }
            Tm[s][n][mcol] = v;
            Hup[s][n][mcol] = 0.f;
        }
    }
    __syncthreads();
    {
        const int n = t & 15, mcol = t >> 4;
        float acc = 0.f;
#pragma unroll
        for (int kk = 0; kk < KN; ++kk) acc += msk[kk]*Qm[n][kk]*Qm[mcol][kk];
        HQ[n][mcol] = acc;
    }
    for (int tt = t; tt < NT_TRI; tt += 256) {
        const int eij = t_ij[tt], ejk = t_jk[tt], eik = t_ik[tt];
        const int a0 = e_i[eij], a1 = e_j[eij];
        const int b0 = e_i[ejk], b1_ = e_j[ejk];
        const int c0 = e_i[eik], c1 = e_j[eik];
        float wprod[NS];
#pragma unroll
        for (int s = 0; s < NS; ++s)
            wprod[s] = sA[s][a0][a1] * sA[s][b0][b1_] * sA[s][c0][c1];
        int un[6]; int nu = 0;
        const int nodes[6] = {a0,a1,b0,b1_,c0,c1};
        for (int ii = 0; ii < 6; ++ii) {
            const int nd = nodes[ii]; bool seen = false;
            for (int jj = 0; jj < nu; ++jj) if (un[jj] == nd) seen = true;
            if (!seen) un[nu++] = nd;
        }
        float cf[6];
        for (int ii = 0; ii < nu; ++ii) {
            const int nd = un[ii];
            float c = 0.f;
            if (nd==b0 || nd==b1_) c += 1.f;
            if (nd==c0 || nd==c1 ) c -= 1.f;
            if (nd==a0 || nd==a1 ) c += 1.f;
            cf[ii] = c;
        }
        for (int ii = 0; ii < nu; ++ii) {
            if (cf[ii] == 0.f) continue;
            for (int jj = 0; jj < nu; ++jj) {
                if (cf[jj] == 0.f) continue;
                const float cc = cf[ii]*cf[jj];
#pragma unroll
                for (int s = 0; s < NS; ++s)
                    atomicAdd(&Hup[s][un[ii]][un[jj]], cc*wprod[s]);
            }
        }
    }
    __syncthreads();
    {
        const int n = t & 15, mcol = t >> 4;
#pragma unroll
        for (int s = 0; s < NS; ++s)
            Tm[NS+s][n][mcol] = HQ[n][mcol] + Hup[s][n][mcol] + TAUF*P2m[n][mcol];
    }
    __syncthreads();

    { // Z_aug: MFMA T(16x16, K-padded to 32) @ xn(16x256). 4 j-tiles per wave.
        ushort_t* Zb = Z + (size_t)b*KN*KAUG;
        const int w = t >> 6, l = t & 63;
        const int lr = l & 15, lk = l >> 4;

        // rowsum -> bias cols; zero pad cols
        if (t < 96) {
            const int m6 = t >> 4, n = t & 15;
            float s = 0.f;
#pragma unroll
            for (int mm = 0; mm < KN; ++mm) s += Tm[m6][n][mm];
            Zb[(size_t)n*KAUG + 1536 + m6] = f2bf(s);
        }
        for (int idx = t; idx < 16*58; idx += 256) {
            const int n = idx / 58, c = 1542 + idx % 58;
            Zb[(size_t)n*KAUG + c] = 0;
        }

        // B-frags: xn columns for this wave's 4 j-tiles (lanes lk>=2 are K-pad)
        short8v bfr[4];
#pragma unroll
        for (int q4 = 0; q4 < 4; ++q4) {
            const int jc = w*64 + q4*16 + lr;
#pragma unroll
            for (int i = 0; i < 8; ++i)
                bfr[q4][i] = (lk < 2) ? (short)xnb[lk*8 + i][jc] : (short)0;
        }
#pragma unroll
        for (int m6 = 0; m6 < 6; ++m6) {
            short8v af = {0,0,0,0,0,0,0,0};
            if (lk < 2) {
                const f32x4 t0 = *(const f32x4*)&Tm[m6][lr][lk*8];
                const f32x4 t1 = *(const f32x4*)&Tm[m6][lr][lk*8 + 4];
                af[0] = (short)f2bf(t0[0]); af[1] = (short)f2bf(t0[1]);
                af[2] = (short)f2bf(t0[2]); af[3] = (short)f2bf(t0[3]);
                af[4] = (short)f2bf(t1[0]); af[5] = (short)f2bf(t1[1]);
                af[6] = (short)f2bf(t1[2]); af[7] = (short)f2bf(t1[3]);
            }
#pragma unroll
            for (int q4 = 0; q4 < 4; ++q4) {
                f32x4 acc = {0.f,0.f,0.f,0.f};
                acc = __builtin_amdgcn_mfma_f32_16x16x32_bf16(af, bfr[q4], acc, 0, 0, 0);
                const int jc = w*64 + q4*16 + lr;
#pragma unroll
                for (int rg = 0; rg < 4; ++rg) {
                    const int n = lk*4 + rg;
                    Zb[(size_t)n*KAUG + m6*256 + jc] = f2bf(acc[rg]);
                }
            }
        }
    }
}

// ---------------------------------------------------------------------------
// LDS-staged MFMA GEMM: C[M][ldo] = A[M][KD] @ Bt[N][KD]^T, 4 waves (2x2).
// EPI 1: +bias, fast-gelu, bf16    EPI 2: outF += acc + bias (in-place resid)
// EPI 3: outF = resid + acc + bias
// ---------------------------------------------------------------------------
template<int BM, int BN, int KD, int EPI>
__global__ __launch_bounds__(256) void gemm_lds(
    const ushort_t* __restrict__ A, const ushort_t* __restrict__ Bt,
    const float* __restrict__ bias, const float* __restrict__ resid,
    float* __restrict__ outF, ushort_t* __restrict__ outH, int ldo)
{
    constexpr int BK = 64;
    constexpr int MF = BM / 32, NF = BN / 32;
    __shared__ ushort_t lA[BM*BK];
    __shared__ ushort_t lB[BN*BK];
    const int t = threadIdx.x;
    const int w = t >> 6, l = t & 63;
    const int wm = w & 1, wn = w >> 1;
    const int lr = l & 15, lk = l >> 4;
    const int brow = blockIdx.x * BM;
    const int bcol = blockIdx.y * BN;

    f32x4 acc[MF][NF];
#pragma unroll
    for (int mf = 0; mf < MF; ++mf)
#pragma unroll
        for (int nt = 0; nt < NF; ++nt)
            acc[mf][nt] = (f32x4){0.f,0.f,0.f,0.f};

    const int byteoff = t * 16;

    for (int kc = 0; kc < KD/BK; ++kc) {
        if (kc) __syncthreads();
#pragma unroll
        for (int c = 0; c < BM/32; ++c) {
            const int bo = c*4096 + byteoff;
            const int row = bo >> 7, kb = bo & 127;
            gload_lds16(A + (size_t)(brow + row)*KD + kc*BK + (kb >> 1), lA + (bo >> 1));
        }
#pragma unroll
        for (int c = 0; c < BN/32; ++c) {
            const int bo = c*4096 + byteoff;
            const int row = bo >> 7, kb = bo & 127;
            gload_lds16(Bt + (size_t)(bcol + row)*KD + kc*BK + (kb >> 1), lB + (bo >> 1));
        }
        __syncthreads();
#pragma unroll
        for (int ks = 0; ks < 2; ++ks) {
            short8v af[MF], bfr[NF];
#pragma unroll
            for (int mf = 0; mf < MF; ++mf)
                af[mf] = *(const short8v*)(lA + (wm*(BM/2) + mf*16 + lr)*BK + ks*32 + lk*8);
#pragma unroll
            for (int nt = 0; nt < NF; ++nt)
                bfr[nt] = *(const short8v*)(lB + (wn*(BN/2) + nt*16 + lr)*BK + ks*32 + lk*8);
#pragma unroll
            for (int mf = 0; mf < MF; ++mf)
#pragma unroll
                for (int nt = 0; nt < NF; ++nt)
                    acc[mf][nt] = __builtin_amdgcn_mfma_f32_16x16x32_bf16(
                        af[mf], bfr[nt], acc[mf][nt], 0, 0, 0);
        }
    }

#pragma unroll
    for (int mf = 0; mf < MF; ++mf) {
#pragma unroll
        for (int nt = 0; nt < NF; ++nt) {
            const int col = bcol + wn*(BN/2) + nt*16 + lr;
#pragma unroll
            for (int rg = 0; rg < 4; ++rg) {
                const int row = brow + wm*(BM/2) + mf*16 + lk*4 + rg;
                const size_t o = (size_t)row * ldo + col;
                const float v = acc[mf][nt][rg];
                if (EPI == 1) {
                    const float u = v + bias[col];
                    const float a = 0.79788456080286536f*(u + 0.044715f*u*u*u);
                    outH[o] = f2bf(u / (1.f + __expf(-2.f*a)));
                } else if (EPI == 2) {
                    outF[o] = outF[o] + v + bias[col];
                } else {
                    outF[o] = resid[o] + v + bias[col];
                }
            }
        }
    }
}

// ---------------------------------------------------------------------------
// Row LayerNorm: in fp32 [8192][256] -> out bf16. One wave per row.
// ---------------------------------------------------------------------------
__global__ __launch_bounds__(256) void ln_rows_kernel(
    const float* __restrict__ in, const float* __restrict__ g,
    const float* __restrict__ bvec, ushort_t* __restrict__ outv)
{
    const int row = blockIdx.x*4 + (threadIdx.x >> 6);
    const int l = threadIdx.x & 63;
    const float4 v = *(const float4*)(in + (size_t)row*DM + l*4);
    float s = v.x + v.y + v.z + v.w;
#pragma unroll
    for (int o = 1; o < 64; o <<= 1) s += __shfl_xor(s, o);
    const float mu = s * (1.f/DM);
    float d0 = v.x-mu, d1 = v.y-mu, d2 = v.z-mu, d3 = v.w-mu;
    float vs = d0*d0 + d1*d1 + d2*d2 + d3*d3;
#pragma unroll
    for (int o = 1; o < 64; o <<= 1) vs += __shfl_xor(vs, o);
    const float rstd = rsqrtf(vs*(1.f/DM) + 1e-5f);
    short4v o4;
    o4[0] = (short)f2bf(d0*rstd*g[l*4+0] + bvec[l*4+0]);
    o4[1] = (short)f2bf(d1*rstd*g[l*4+1] + bvec[l*4+1]);
    o4[2] = (short)f2bf(d2*rstd*g[l*4+2] + bvec[l*4+2]);
    o4[3] = (short)f2bf(d3*rstd*g[l*4+3] + bvec[l*4+3]);
    *(short4v*)(outv + (size_t)row*DM + l*4) = o4;
}

extern "C" void kernel_launch(void* const* d_in, const int* in_sizes, int n_in,
                              void* d_out, int out_size, void* d_ws, size_t ws_size,
                              hipStream_t stream) {
    const float* x          = (const float*)d_in[0];
    const float* mask       = (const float*)d_in[1];
    const int*   e_i        = (const int*)  d_in[5];
    const int*   e_j        = (const int*)  d_in[6];
    const int*   t_ij       = (const int*)  d_in[7];
    const int*   t_jk       = (const int*)  d_in[8];
    const int*   t_ik       = (const int*)  d_in[9];
    const float* log_scales = (const float*)d_in[10];
    const float* Wg         = (const float*)d_in[11];
    const float* bg         = (const float*)d_in[12];
    const float* Wv0        = (const float*)d_in[13];
    const float* bv0        = (const float*)d_in[14];
    const float* We         = (const float*)d_in[15];
    const float* be         = (const float*)d_in[16];
    const float* Wout       = (const float*)d_in[17];
    const float* bout       = (const float*)d_in[18];
    const float* g1         = (const float*)d_in[19];
    const float* b1         = (const float*)d_in[20];
    const float* g2         = (const float*)d_in[21];
    const float* b2         = (const float*)d_in[22];
    const float* Wf1        = (const float*)d_in[23];
    const float* bf1        = (const float*)d_in[24];
    const float* Wf2        = (const float*)d_in[25];
    const float* bf2        = (const float*)d_in[26];

    char* wsb = (char*)d_ws;
    ushort_t* wstack = (ushort_t*)(wsb + OFF_WSTACK);
    ushort_t* wf1t   = (ushort_t*)(wsb + OFF_WF1T);
    ushort_t* wf2t   = (ushort_t*)(wsb + OFF_WF2T);
    ushort_t* Z      = (ushort_t*)(wsb + OFF_Z);
    ushort_t* H      = (ushort_t*)(wsb + OFF_H);    // aliases Z
    ushort_t* ln2    = (ushort_t*)(wsb + OFF_LN2);
    float*    out    = (float*)d_out;

    // 1. weight prep (fuse + 2 transposes, one kernel)
    hipLaunchKernelGGL(prep_kernel, dim3(230), dim3(256), 0, stream,
                       Wv0, bv0, We, be, Wout, Wf1, Wf2, wstack, wf1t, wf2t);
    // 2. topology -> Z_aug
    hipLaunchKernelGGL(attn_topo_kernel, dim3(NBATCH), dim3(256), 0, stream,
                       x, mask, e_i, e_j, t_ij, t_jk, t_ik, log_scales,
                       Wg, bg, g1, b1, Z);
    // 3. x2 = x + Z_aug @ Wstack + bout   (M=8192, K=1600, N=256) -> d_out
    hipLaunchKernelGGL((gemm_lds<64,64,KAUG,3>), dim3(128,4), dim3(256), 0, stream,
                       Z, wstack, bout, x, out, (ushort_t*)nullptr, 256);
    // 4. ln2 = LN(x2) bf16
    hipLaunchKernelGGL(ln_rows_kernel, dim3(2048), dim3(256), 0, stream,
                       out, g2, b2, ln2);
    // 5. H = gelu(ln2 @ Wf1 + bf1)   (M=8192, K=256, N=1024)
    hipLaunchKernelGGL((gemm_lds<128,128,256,1>), dim3(64,8), dim3(256), 0, stream,
                       ln2, wf1t, bf1, (const float*)nullptr,
                       (float*)nullptr, H, 1024);
    // 6. out += H @ Wf2 + bf2   (M=8192, K=1024, N=256)
    hipLaunchKernelGGL((gemm_lds<64,64,1024,2>), dim3(128,4), dim3(256), 0, stream,
                       H, wf2t, bf2, (const float*)nullptr,
                       out, (ushort_t*)nullptr, 256);
}

// Round 6
// 122.199 us; speedup vs baseline: 1.0754x; 1.0754x over previous
//
#include <hip/hip_runtime.h>
#include <math.h>

#define KN 16
#define DM 256
#define NS 3
#define NE 120
#define NT_TRI 560
#define NBATCH 512
#define TAUF 1e-4f
#define KAUG 1600            // 1536 + 6 bias cols + 58 zero pad

typedef unsigned short ushort_t;
typedef __attribute__((ext_vector_type(8))) short short8v;
typedef __attribute__((ext_vector_type(4))) short short4v;
typedef __attribute__((ext_vector_type(4))) float f32x4;

// ---- workspace byte offsets (~32.3 MB total) ----
#define OFF_WSTACK 0u          // bf16 [256][1600]                       819200
#define OFF_WF1T   819200u     // bf16 [1024][256]                       524288
#define OFF_WF2T   1343488u    // bf16 [256][1024]                       524288
#define OFF_TOPO   1867776u    // f32 Q[256],P2[256],adj[256]; int tri[560][2]  (8192)
#define OFF_Z      1875968u    // bf16 [8192][1600]                    26214400
#define OFF_H      1875968u    // bf16 [8192][1024] aliases Z
#define OFF_LN2    28090368u   // bf16 [8192][256]                      4194304

__device__ __forceinline__ ushort_t f2bf(float f) {
    union { float f; unsigned int u; } v; v.f = f;
    unsigned int r = v.u + 0x7FFFu + ((v.u >> 16) & 1u);
    return (ushort_t)(r >> 16);
}
__device__ __forceinline__ void gload_lds16(const void* g, void* l) {
    auto gp = (const __attribute__((address_space(1))) unsigned int*)(unsigned long long)(g);
    auto lp = (__attribute__((address_space(3))) unsigned int*)(unsigned long long)(l);
    __builtin_amdgcn_global_load_lds(gp, lp, 16, 0, 0);
}

// ---------------------------------------------------------------------------
// Prep: bid<102 fuse Wv0/We x Wout -> Wstack ; bid<166 T(Wf1) ; bid<230 T(Wf2)
//       bid==230 topology tables (Q, P2, adj, packed triangles)
// ---------------------------------------------------------------------------
__global__ __launch_bounds__(256) void prep_kernel(
    const float* __restrict__ Wv0, const float* __restrict__ bv0,
    const float* __restrict__ We,  const float* __restrict__ be,
    const float* __restrict__ Wout,
    const float* __restrict__ Wf1, const float* __restrict__ Wf2,
    const int* __restrict__ e_i, const int* __restrict__ e_j,
    const int* __restrict__ t_ij, const int* __restrict__ t_jk, const int* __restrict__ t_ik,
    ushort_t* __restrict__ wstack, ushort_t* __restrict__ wf1t,
    ushort_t* __restrict__ wf2t,
    float* __restrict__ topoF, int* __restrict__ triPk)
{
    __shared__ float lhs[16][DM];
    __shared__ float tile[64][65];
    __shared__ int   eidxL[256];
    const int bid = blockIdx.x;
    const int j = threadIdx.x;

    if (bid == 230) {   // topology tables
        eidxL[j] = -1;
        __syncthreads();
        if (j < NE) {
            const int i = e_i[j], jn = e_j[j];
            eidxL[i*16 + jn] = j; eidxL[jn*16 + i] = j;
        }
        __syncthreads();
        const int n = j >> 4, m = j & 15;
        float q, p2, adj;
        if (n != m) {
            const int e = eidxL[j];
            if (e >= 0) { q = (m == e_j[e]) ? 1.f : -1.f; p2 = 1.f; adj = 1.f; }
            else        { q = 0.f; p2 = 0.f; adj = 0.f; }
        } else {
            q = 0.f; p2 = 0.f; adj = 0.f;
            for (int kk = 0; kk < KN; ++kk) {
                if (kk == n) continue;
                const int e = eidxL[n*16 + kk];
                if (e >= 0) { q += (n == e_j[e]) ? 1.f : -1.f; p2 += 1.f; }
            }
        }
        topoF[j] = q; topoF[256 + j] = p2; topoF[512 + j] = adj;
        for (int tt = j; tt < NT_TRI; tt += 256) {
            const int eij = t_ij[tt], ejk = t_jk[tt], eik = t_ik[tt];
            const int a0 = e_i[eij], a1 = e_j[eij];
            const int b0 = e_i[ejk], b1v = e_j[ejk];
            const int c0 = e_i[eik], c1 = e_j[eik];
            // mid = shared node of eij and ejk (the only node with nonzero |B1|B2 coef)
            const int mid = (b0 == a0 || b0 == a1) ? b0 : b1v;
            triPk[2*tt]   = a0 | (a1 << 8) | (b0 << 16) | (b1v << 24);
            triPk[2*tt+1] = c0 | (c1 << 8) | (mid << 16);
        }
        return;
    }

    if (bid < 102) {
        const int m = bid / 17, by = bid % 17;
        const int path = m / 3, s = m % 3;
        const float* __restrict__ Wo = Wout + (size_t)m*DM*DM;
        if (by == 16) {   // fused bias -> K-row 1536+m of Wstack
            const float* bv = (path == 0) ? bv0 : be;
            const float f = (path == 0) ? 1.0f : 0.5f;   // 1_E = 0.5*|B1|^T 1_K
            float acc = 0.f;
            for (int k = 0; k < DM; ++k)
                acc += bv[s*DM + k] * f * Wo[k*DM + j];
            wstack[(size_t)j*KAUG + 1536 + m] = f2bf(acc);
            if (m == 0)
                for (int c = 1542; c < KAUG; ++c)
                    wstack[(size_t)j*KAUG + c] = 0;
            return;
        }
        const float* src = (path == 0) ? Wv0 : We;
        const int i0 = by * 16;
        for (int r = 0; r < 16; ++r)
            lhs[r][j] = src[(size_t)(i0 + r)*(NS*DM) + s*DM + j];
        __syncthreads();
        float acc[16];
#pragma unroll
        for (int r = 0; r < 16; ++r) acc[r] = 0.f;
        for (int k = 0; k < DM; ++k) {
            const float w = Wo[k*DM + j];
#pragma unroll
            for (int r = 0; r < 16; ++r) acc[r] += lhs[r][k] * w;
        }
#pragma unroll
        for (int r = 0; r < 16; ++r)
            wstack[(size_t)j*KAUG + m*DM + i0 + r] = f2bf(acc[r]);
        return;
    }

    // transpose branches
    const float* in; ushort_t* outp; int R, C, rt, ct;
    if (bid < 166) {
        const int q = bid - 102;
        in = Wf1; outp = wf1t; R = 256; C = 1024;
        rt = (q >> 4) * 64; ct = (q & 15) * 64;
    } else {
        const int q = bid - 166;
        in = Wf2; outp = wf2t; R = 1024; C = 256;
        rt = (q >> 2) * 64; ct = (q & 3) * 64;
    }
#pragma unroll
    for (int q2 = 0; q2 < 16; ++q2) {
        const int idx = q2*256 + j;
        const int r = idx >> 6, c = idx & 63;
        tile[r][c] = in[(size_t)(rt + r)*C + ct + c];
    }
    __syncthreads();
#pragma unroll
    for (int q2 = 0; q2 < 16; ++q2) {
        const int idx = q2*256 + j;
        const int cc = idx >> 6, rr = idx & 63;
        outp[(size_t)(ct + cc)*R + rt + rr] = f2bf(tile[rr][cc]);
    }
}

// ---------------------------------------------------------------------------
// Per-batch topology, straight-line: LN -> P -> A_s/T0 -> tri -> T1 -> Z(MFMA)
// thread t: n = t>>4 (row), m = t&15 ; lanes sharing n are consecutive.
// ---------------------------------------------------------------------------
__global__ __launch_bounds__(256) void attn_topo_kernel(
    const float* __restrict__ x, const float* __restrict__ mask,
    const float* __restrict__ log_scales,
    const float* __restrict__ Wg, const float* __restrict__ bg,
    const float* __restrict__ g1, const float* __restrict__ b1,
    const float* __restrict__ topoF, const int* __restrict__ triPk,
    ushort_t* __restrict__ Z)
{
    const int b = blockIdx.x;
    const int t = threadIdx.x;
    const int n = t >> 4, m = t & 15;

    __shared__ ushort_t xnbT[DM][16];    // xn transposed [col][node] bf16, 8 KB
    __shared__ float Plds[KN][KN];
    __shared__ float mskL[KN];
    __shared__ float QL[256];
    __shared__ float P2L[256];
    __shared__ float adjL[256];
    __shared__ float sA[NS][KN][KN];
    __shared__ float Hupd[NS*KN];
    __shared__ ushort_t Tbf[6][KN][32];  // K padded to 32 (cols 16..31 zero), 6 KB

    // ---- phase 0: tables, mask, LN, P ----
    QL[t]  = topoF[t];
    P2L[t] = topoF[256 + t];
    adjL[t] = topoF[512 + t];
    if (t < KN) mskL[t] = mask[b*KN + t];

    float xv[16];
    {
        const int cg = m * 16;
        const float* xr = x + (size_t)(b*KN + n)*DM + cg;
        const f32x4 v0 = *(const f32x4*)(xr);
        const f32x4 v1 = *(const f32x4*)(xr + 4);
        const f32x4 v2 = *(const f32x4*)(xr + 8);
        const f32x4 v3 = *(const f32x4*)(xr + 12);
#pragma unroll
        for (int q = 0; q < 4; ++q) { xv[q] = v0[q]; xv[4+q] = v1[q]; xv[8+q] = v2[q]; xv[12+q] = v3[q]; }
        float ssum = 0.f;
#pragma unroll
        for (int q = 0; q < 16; ++q) ssum += xv[q];
#pragma unroll
        for (int o = 1; o < 16; o <<= 1) ssum += __shfl_xor(ssum, o);
        const float mu = ssum * (1.f/DM);
        float vsum = 0.f;
#pragma unroll
        for (int q = 0; q < 16; ++q) { const float d = xv[q]-mu; vsum += d*d; }
#pragma unroll
        for (int o = 1; o < 16; o <<= 1) vsum += __shfl_xor(vsum, o);
        const float rstd = rsqrtf(vsum*(1.f/DM) + 1e-5f);
        const f32x4 ga = *(const f32x4*)(g1 + cg),   gb = *(const f32x4*)(g1 + cg + 4);
        const f32x4 gc = *(const f32x4*)(g1 + cg + 8), gd = *(const f32x4*)(g1 + cg + 12);
        const f32x4 ba = *(const f32x4*)(b1 + cg),   bb = *(const f32x4*)(b1 + cg + 4);
        const f32x4 bc = *(const f32x4*)(b1 + cg + 8), bd = *(const f32x4*)(b1 + cg + 12);
        float gg[16], bbv[16];
#pragma unroll
        for (int q = 0; q < 4; ++q) {
            gg[q] = ga[q]; gg[4+q] = gb[q]; gg[8+q] = gc[q]; gg[12+q] = gd[q];
            bbv[q] = ba[q]; bbv[4+q] = bb[q]; bbv[8+q] = bc[q]; bbv[12+q] = bd[q];
        }
#pragma unroll
        for (int q = 0; q < 16; ++q) {
            xv[q] = (xv[q]-mu)*rstd*gg[q] + bbv[q];
            xnbT[cg + q][n] = f2bf(xv[q]);
        }
    }

    { // P[n][c] via per-thread partials + 4-round butterfly over the 16 m-lanes
        float part[16];
#pragma unroll
        for (int c = 0; c < 16; ++c) part[c] = 0.f;
        const int cg = m * 16;
#pragma unroll
        for (int q = 0; q < 16; ++q) {
            const float xq = xv[q];
            const float* wr = Wg + (size_t)(cg + q)*KN;
            const f32x4 w0 = *(const f32x4*)(wr);
            const f32x4 w1 = *(const f32x4*)(wr + 4);
            const f32x4 w2 = *(const f32x4*)(wr + 8);
            const f32x4 w3 = *(const f32x4*)(wr + 12);
            part[0]  += xq*w0[0]; part[1]  += xq*w0[1]; part[2]  += xq*w0[2]; part[3]  += xq*w0[3];
            part[4]  += xq*w1[0]; part[5]  += xq*w1[1]; part[6]  += xq*w1[2]; part[7]  += xq*w1[3];
            part[8]  += xq*w2[0]; part[9]  += xq*w2[1]; part[10] += xq*w2[2]; part[11] += xq*w2[3];
            part[12] += xq*w3[0]; part[13] += xq*w3[1]; part[14] += xq*w3[2]; part[15] += xq*w3[3];
        }
        const int b0 = t & 1, b1b = (t>>1)&1, b2 = (t>>2)&1, b3 = (t>>3)&1;
        float p8[8];
#pragma unroll
        for (int c2 = 0; c2 < 8; ++c2) {
            const float keep = b0 ? part[2*c2+1] : part[2*c2];
            const float send = b0 ? part[2*c2]   : part[2*c2+1];
            p8[c2] = keep + __shfl_xor(send, 1);
        }
        float p4[4];
#pragma unroll
        for (int c2 = 0; c2 < 4; ++c2) {
            const float keep = b1b ? p8[2*c2+1] : p8[2*c2];
            const float send = b1b ? p8[2*c2]   : p8[2*c2+1];
            p4[c2] = keep + __shfl_xor(send, 2);
        }
        float p2v[2];
#pragma unroll
        for (int c2 = 0; c2 < 2; ++c2) {
            const float keep = b2 ? p4[2*c2+1] : p4[2*c2];
            const float send = b2 ? p4[2*c2]   : p4[2*c2+1];
            p2v[c2] = keep + __shfl_xor(send, 4);
        }
        const float keep = b3 ? p2v[1] : p2v[0];
        const float send = b3 ? p2v[0] : p2v[1];
        Plds[n][m] = keep + __shfl_xor(send, 8) + bg[m];
    }
    __syncthreads();   // barrier A

    // ---- phase 1: d2 -> sA, T0 (node path), HQ; zero Hupd + Tbf pads ----
    float T0[NS], hq;
    {
        float d2 = 0.f;
#pragma unroll
        for (int k = 0; k < KN; ++k) {
            const float dd = Plds[n][k] - Plds[m][k];
            d2 += dd*dd;
        }
        const float m2v = mskL[n]*mskL[m];
        const float dm = (d2 > 0.f) ? sqrtf(d2)*m2v : 0.f;
        const float dmsq = dm*dm;
        const float adjv = adjL[t];
#pragma unroll
        for (int s = 0; s < NS; ++s) {
            const float sig2 = expf(2.f*log_scales[s]);
            const float a = expf(-dmsq/(2.f*sig2 + 1e-8f)) * m2v;
            sA[s][n][m] = a;
            const float am = a * adjv;
            float rsum = am;
#pragma unroll
            for (int o = 1; o < 16; o <<= 1) rsum += __shfl_xor(rsum, o);
            const float tv = (m == n) ? (TAUF + rsum) : (-am);
            T0[s] = tv;
            Tbf[s][n][m] = f2bf(tv);
        }
        hq = 0.f;
#pragma unroll
        for (int k = 0; k < KN; ++k)
            hq += mskL[k]*QL[n*16 + k]*QL[m*16 + k];
        if (t < NS*KN) Hupd[t] = 0.f;
#pragma unroll
        for (int idx = 0; idx < 6; ++idx) {   // zero Tbf[.][.][16..31]
            const int e2 = idx*256 + t;
            Tbf[e2 >> 8][(e2 >> 4) & 15][16 + (e2 & 15)] = 0;
        }
    }
    __syncthreads();   // barrier B

    // ---- phase 2: triangles -> diagonal Hupd ----
    for (int tt = t; tt < NT_TRI; tt += 256) {
        const int w0 = triPk[2*tt], w1 = triPk[2*tt+1];
        const int a0 = w0 & 255, a1 = (w0 >> 8) & 255;
        const int b0 = (w0 >> 16) & 255, b1v = (w0 >> 24) & 255;
        const int c0 = w1 & 255, c1 = (w1 >> 8) & 255, mid = (w1 >> 16) & 255;
#pragma unroll
        for (int s = 0; s < NS; ++s)
            atomicAdd(&Hupd[s*KN + mid],
                      4.f * sA[s][a0][a1] * sA[s][b0][b1v] * sA[s][c0][c1]);
    }
    __syncthreads();   // barrier C

    // ---- phase 3: T1 (edge path), rowsums -> Z bias cols, pad cols ----
    ushort_t* Zb = Z + (size_t)b*KN*KAUG;
    {
        float T1[NS];
        const float p2v = P2L[t];
#pragma unroll
        for (int s = 0; s < NS; ++s) {
            const float tv = hq + TAUF*p2v + ((m == n) ? Hupd[s*KN + n] : 0.f);
            T1[s] = tv;
            Tbf[NS + s][n][m] = f2bf(tv);
        }
        float sv[6] = {T0[0], T0[1], T0[2], T1[0], T1[1], T1[2]};
#pragma unroll
        for (int q = 0; q < 6; ++q) {
            float v = sv[q];
#pragma unroll
            for (int o = 1; o < 16; o <<= 1) v += __shfl_xor(v, o);
            sv[q] = v;
        }
        const float wv = (m==0)?sv[0]:(m==1)?sv[1]:(m==2)?sv[2]:(m==3)?sv[3]:(m==4)?sv[4]:sv[5];
        if (m < 6) Zb[(size_t)n*KAUG + 1536 + m] = f2bf(wv);
        for (int idx = t; idx < 58*KN; idx += 256) {
            const int nn = idx / 58, c = 1542 + idx % 58;
            Zb[(size_t)nn*KAUG + c] = 0;
        }
    }
    __syncthreads();   // barrier D

    // ---- phase 4: Z = T @ xn via MFMA (K=16 padded to 32) ----
    {
        const int w = t >> 6, l = t & 63;
        const int lr = l & 15, lk = l >> 4;
        short8v bfr[4];
#pragma unroll
        for (int q4 = 0; q4 < 4; ++q4) {
            const int jc = w*64 + q4*16 + lr;
            bfr[q4] = *(const short8v*)&xnbT[jc][(lk & 1)*8];  // lk>=2 irrelevant (A pad=0)
        }
#pragma unroll
        for (int m6 = 0; m6 < 6; ++m6) {
            const short8v af = *(const short8v*)&Tbf[m6][lr][lk*8];
#pragma unroll
            for (int q4 = 0; q4 < 4; ++q4) {
                f32x4 acc = {0.f,0.f,0.f,0.f};
                acc = __builtin_amdgcn_mfma_f32_16x16x32_bf16(af, bfr[q4], acc, 0, 0, 0);
                const int jc = w*64 + q4*16 + lr;
#pragma unroll
                for (int rg = 0; rg < 4; ++rg)
                    Zb[(size_t)(lk*4 + rg)*KAUG + m6*256 + jc] = f2bf(acc[rg]);
            }
        }
    }
}

// ---------------------------------------------------------------------------
// LDS-staged MFMA GEMM: C[M][ldo] = A[M][KD] @ Bt[N][KD]^T, 4 waves (2x2).
// EPI 1: +bias, fast-gelu, bf16    EPI 2: outF += acc + bias
// EPI 3: outF = resid + acc + bias
// ---------------------------------------------------------------------------
template<int BM, int BN, int KD, int EPI>
__global__ __launch_bounds__(256) void gemm_lds(
    const ushort_t* __restrict__ A, const ushort_t* __restrict__ Bt,
    const float* __restrict__ bias, const float* __restrict__ resid,
    float* __restrict__ outF, ushort_t* __restrict__ outH, int ldo)
{
    constexpr int BK = 64;
    constexpr int MF = BM / 32, NF = BN / 32;
    __shared__ ushort_t lA[BM*BK];
    __shared__ ushort_t lB[BN*BK];
    const int t = threadIdx.x;
    const int w = t >> 6, l = t & 63;
    const int wm = w & 1, wn = w >> 1;
    const int lr = l & 15, lk = l >> 4;
    const int brow = blockIdx.x * BM;
    const int bcol = blockIdx.y * BN;

    f32x4 acc[MF][NF];
#pragma unroll
    for (int mf = 0; mf < MF; ++mf)
#pragma unroll
        for (int nt = 0; nt < NF; ++nt)
            acc[mf][nt] = (f32x4){0.f,0.f,0.f,0.f};

    const int byteoff = t * 16;

    for (int kc = 0; kc < KD/BK; ++kc) {
        if (kc) __syncthreads();
#pragma unroll
        for (int c = 0; c < BM/32; ++c) {
            const int bo = c*4096 + byteoff;
            const int row = bo >> 7, kb = bo & 127;
            gload_lds16(A + (size_t)(brow + row)*KD + kc*BK + (kb >> 1), lA + (bo >> 1));
        }
#pragma unroll
        for (int c = 0; c < BN/32; ++c) {
            const int bo = c*4096 + byteoff;
            const int row = bo >> 7, kb = bo & 127;
            gload_lds16(Bt + (size_t)(bcol + row)*KD + kc*BK + (kb >> 1), lB + (bo >> 1));
        }
        __syncthreads();
#pragma unroll
        for (int ks = 0; ks < 2; ++ks) {
            short8v af[MF], bfr[NF];
#pragma unroll
            for (int mf = 0; mf < MF; ++mf)
                af[mf] = *(const short8v*)(lA + (wm*(BM/2) + mf*16 + lr)*BK + ks*32 + lk*8);
#pragma unroll
            for (int nt = 0; nt < NF; ++nt)
                bfr[nt] = *(const short8v*)(lB + (wn*(BN/2) + nt*16 + lr)*BK + ks*32 + lk*8);
#pragma unroll
            for (int mf = 0; mf < MF; ++mf)
#pragma unroll
                for (int nt = 0; nt < NF; ++nt)
                    acc[mf][nt] = __builtin_amdgcn_mfma_f32_16x16x32_bf16(
                        af[mf], bfr[nt], acc[mf][nt], 0, 0, 0);
        }
    }

#pragma unroll
    for (int mf = 0; mf < MF; ++mf) {
#pragma unroll
        for (int nt = 0; nt < NF; ++nt) {
            const int col = bcol + wn*(BN/2) + nt*16 + lr;
#pragma unroll
            for (int rg = 0; rg < 4; ++rg) {
                const int row = brow + wm*(BM/2) + mf*16 + lk*4 + rg;
                const size_t o = (size_t)row * ldo + col;
                const float v = acc[mf][nt][rg];
                if (EPI == 1) {
                    const float u = v + bias[col];
                    const float a = 0.79788456080286536f*(u + 0.044715f*u*u*u);
                    outH[o] = f2bf(u / (1.f + __expf(-2.f*a)));
                } else if (EPI == 2) {
                    outF[o] = outF[o] + v + bias[col];
                } else {
                    outF[o] = resid[o] + v + bias[col];
                }
            }
        }
    }
}

// ---------------------------------------------------------------------------
// Row LayerNorm: in fp32 [8192][256] -> out bf16. One wave per row.
// ---------------------------------------------------------------------------
__global__ __launch_bounds__(256) void ln_rows_kernel(
    const float* __restrict__ in, const float* __restrict__ g,
    const float* __restrict__ bvec, ushort_t* __restrict__ outv)
{
    const int row = blockIdx.x*4 + (threadIdx.x >> 6);
    const int l = threadIdx.x & 63;
    const float4 v = *(const float4*)(in + (size_t)row*DM + l*4);
    float s = v.x + v.y + v.z + v.w;
#pragma unroll
    for (int o = 1; o < 64; o <<= 1) s += __shfl_xor(s, o);
    const float mu = s * (1.f/DM);
    float d0 = v.x-mu, d1 = v.y-mu, d2 = v.z-mu, d3 = v.w-mu;
    float vs = d0*d0 + d1*d1 + d2*d2 + d3*d3;
#pragma unroll
    for (int o = 1; o < 64; o <<= 1) vs += __shfl_xor(vs, o);
    const float rstd = rsqrtf(vs*(1.f/DM) + 1e-5f);
    short4v o4;
    o4[0] = (short)f2bf(d0*rstd*g[l*4+0] + bvec[l*4+0]);
    o4[1] = (short)f2bf(d1*rstd*g[l*4+1] + bvec[l*4+1]);
    o4[2] = (short)f2bf(d2*rstd*g[l*4+2] + bvec[l*4+2]);
    o4[3] = (short)f2bf(d3*rstd*g[l*4+3] + bvec[l*4+3]);
    *(short4v*)(outv + (size_t)row*DM + l*4) = o4;
}

extern "C" void kernel_launch(void* const* d_in, const int* in_sizes, int n_in,
                              void* d_out, int out_size, void* d_ws, size_t ws_size,
                              hipStream_t stream) {
    const float* x          = (const float*)d_in[0];
    const float* mask       = (const float*)d_in[1];
    const int*   e_i        = (const int*)  d_in[5];
    const int*   e_j        = (const int*)  d_in[6];
    const int*   t_ij       = (const int*)  d_in[7];
    const int*   t_jk       = (const int*)  d_in[8];
    const int*   t_ik       = (const int*)  d_in[9];
    const float* log_scales = (const float*)d_in[10];
    const float* Wg         = (const float*)d_in[11];
    const float* bg         = (const float*)d_in[12];
    const float* Wv0        = (const float*)d_in[13];
    const float* bv0        = (const float*)d_in[14];
    const float* We         = (const float*)d_in[15];
    const float* be         = (const float*)d_in[16];
    const float* Wout       = (const float*)d_in[17];
    const float* bout       = (const float*)d_in[18];
    const float* g1         = (const float*)d_in[19];
    const float* b1         = (const float*)d_in[20];
    const float* g2         = (const float*)d_in[21];
    const float* b2         = (const float*)d_in[22];
    const float* Wf1        = (const float*)d_in[23];
    const float* bf1        = (const float*)d_in[24];
    const float* Wf2        = (const float*)d_in[25];
    const float* bf2        = (const float*)d_in[26];

    char* wsb = (char*)d_ws;
    ushort_t* wstack = (ushort_t*)(wsb + OFF_WSTACK);
    ushort_t* wf1t   = (ushort_t*)(wsb + OFF_WF1T);
    ushort_t* wf2t   = (ushort_t*)(wsb + OFF_WF2T);
    float*    topoF  = (float*)   (wsb + OFF_TOPO);
    int*      triPk  = (int*)     (wsb + OFF_TOPO + 3072);
    ushort_t* Z      = (ushort_t*)(wsb + OFF_Z);
    ushort_t* H      = (ushort_t*)(wsb + OFF_H);    // aliases Z
    ushort_t* ln2    = (ushort_t*)(wsb + OFF_LN2);
    float*    out    = (float*)d_out;

    // 1. weight prep + topology tables
    hipLaunchKernelGGL(prep_kernel, dim3(231), dim3(256), 0, stream,
                       Wv0, bv0, We, be, Wout, Wf1, Wf2,
                       e_i, e_j, t_ij, t_jk, t_ik,
                       wstack, wf1t, wf2t, topoF, triPk);
    // 2. topology -> Z_aug
    hipLaunchKernelGGL(attn_topo_kernel, dim3(NBATCH), dim3(256), 0, stream,
                       x, mask, log_scales, Wg, bg, g1, b1, topoF, triPk, Z);
    // 3. x2 = x + Z_aug @ Wstack + bout   (M=8192, K=1600, N=256) -> d_out
    hipLaunchKernelGGL((gemm_lds<64,64,KAUG,3>), dim3(128,4), dim3(256), 0, stream,
                       Z, wstack, bout, x, out, (ushort_t*)nullptr, 256);
    // 4. ln2 = LN(x2) bf16
    hipLaunchKernelGGL(ln_rows_kernel, dim3(2048), dim3(256), 0, stream,
                       out, g2, b2, ln2);
    // 5. H = gelu(ln2 @ Wf1 + bf1)   (M=8192, K=256, N=1024)
    hipLaunchKernelGGL((gemm_lds<128,128,256,1>), dim3(64,8), dim3(256), 0, stream,
                       ln2, wf1t, bf1, (const float*)nullptr,
                       (float*)nullptr, H, 1024);
    // 6. out += H @ Wf2 + bf2   (M=8192, K=1024, N=256)
    hipLaunchKernelGGL((gemm_lds<64,64,1024,2>), dim3(128,4), dim3(256), 0, stream,
                       H, wf2t, bf2, (const float*)nullptr,
                       out, (ushort_t*)nullptr, 256);
}